// Round 2
// baseline (65.282 us; speedup 1.0000x reference)
//
#include <hip/hip_runtime.h>
#include <hip/hip_bf16.h>

typedef __attribute__((ext_vector_type(8))) short short8;
typedef __attribute__((ext_vector_type(4))) float f32x4;

#define ALPHA 0.2f
#define NEG_INF -9e15f
#define OUT_ROWS 126

__device__ __forceinline__ unsigned short f2bf(float x) {
    union { float f; unsigned int u; } v; v.f = x;
    unsigned int r = v.u + 0x7FFFu + ((v.u >> 16) & 1u);
    return (unsigned short)(r >> 16);
}
__device__ __forceinline__ float bf2f(unsigned short x) {
    union { unsigned int u; float f; } v; v.u = ((unsigned int)x) << 16;
    return v.f;
}

// Prep: W [128][128] f32 row-major -> bf16 B-fragment table in ws.
// Fragment fi = (wcg*4 + kk)*4 + ni, lane 0..63:
//   elem j = W[kk*32 + lg*8 + j][wcg*64 + ni*16 + (lane&15)], lg = (lane>>4)&3
// stored at ws + (fi*64 + lane)*8 shorts (16B per lane, coalesced reads later).
__global__ void prep_wt(const float* __restrict__ W, unsigned short* __restrict__ ws) {
    int q = blockIdx.x * 256 + threadIdx.x;      // 0..2047
    int lane = q & 63;
    int fi = q >> 6;                              // 0..31
    int ni = fi & 3;
    int kk = (fi >> 2) & 3;
    int wcg = fi >> 4;
    int n = wcg * 64 + ni * 16 + (lane & 15);
    int k0 = kk * 32 + ((lane >> 4) & 3) * 8;
    short8 o;
    #pragma unroll
    for (int j = 0; j < 8; ++j) o[j] = (short)f2bf(W[(k0 + j) * 128 + n]);
    *(short8*)(ws + (size_t)q * 8) = o;
}

// One block: 126 output rows of one batch. h tile (bf16, swizzled) -> MFMA
// GEMM with B-frags streamed from ws -> Wh bf16 back into the same LDS ->
// windowed attention + combine. LDS ~37KB => 4 blocks/CU.
__global__ __launch_bounds__(256, 4)
void gat_fused(const float* __restrict__ h, const int* __restrict__ opm,
               const unsigned short* __restrict__ ws, const float* __restrict__ a,
               float* __restrict__ out, int N) {
    __shared__ __align__(16) char smem[32768];   // h tile bf16 -> Wh bf16
    __shared__ float a_s[256];
    __shared__ float wh1_s[128];
    __shared__ float wh2_s[128];
    __shared__ float att_s[128][4];

    const int t = threadIdx.x;
    const int b = blockIdx.y;
    const int row_start = blockIdx.x * OUT_ROWS;
    const int out_rows = min(OUT_ROWS, N - row_start);
    const float* hB = h + (size_t)b * N * 128;
    float* outB = out + (size_t)b * N * 128;

    a_s[t] = a[t];

    // ---- stage h tile (bf16, swizzled); rows wrap mod N (handles roll) ----
    #pragma unroll
    for (int i = 0; i < 16; ++i) {
        int idx4 = t + i * 256;
        int r = idx4 >> 5;
        int c = (idx4 & 31) << 2;
        int g = row_start - 1 + r;
        if (g < 0) g += N;
        if (g >= N) g -= N;
        float4 h4 = *(const float4*)(hB + (size_t)g * 128 + c);
        ushort4 p = make_ushort4(f2bf(h4.x), f2bf(h4.y), f2bf(h4.z), f2bf(h4.w));
        *(ushort4*)(smem + r * 256 + ((c * 2) ^ ((r & 7) << 4))) = p;
    }
    __syncthreads();

    // ---- GEMM: Wh[128][128] = hTile @ W, bf16 MFMA 16x16x32 ----
    const int lane = t & 63;
    const int wave = t >> 6;
    const int wr = (wave >> 1) << 6;             // 2x2 waves of 64x64
    const int wcg = wave & 1;
    const int wc = wcg << 6;
    const int l15 = lane & 15;
    const int lg = (lane >> 4) & 3;

    f32x4 acc[4][4];
    #pragma unroll
    for (int mi = 0; mi < 4; ++mi)
        #pragma unroll
        for (int ni = 0; ni < 4; ++ni)
            acc[mi][ni] = (f32x4){0.f, 0.f, 0.f, 0.f};

    const short8* wsv = (const short8*)ws;
    #pragma unroll
    for (int kk = 0; kk < 4; ++kk) {
        int kbyte = (kk << 6) + (lg << 4);       // byte offset along K (8 bf16)
        short8 af[4], bfr[4];
        #pragma unroll
        for (int ni = 0; ni < 4; ++ni)
            bfr[ni] = wsv[(((wcg << 2) + kk) * 4 + ni) * 64 + lane];
        #pragma unroll
        for (int mi = 0; mi < 4; ++mi) {
            int m = wr + (mi << 4) + l15;
            af[mi] = *(const short8*)(smem + m * 256 + (kbyte ^ ((m & 7) << 4)));
        }
        #pragma unroll
        for (int mi = 0; mi < 4; ++mi)
            #pragma unroll
            for (int ni = 0; ni < 4; ++ni)
                acc[mi][ni] = __builtin_amdgcn_mfma_f32_16x16x32_bf16(
                    af[mi], bfr[ni], acc[mi][ni], 0, 0, 0);
    }
    __syncthreads();

    // ---- spill Wh to LDS as bf16 (swizzled), overwriting h tile ----
    // C/D layout: col = lane&15, row = (lane>>4)*4 + reg  [HW-verified]
    #pragma unroll
    for (int mi = 0; mi < 4; ++mi) {
        #pragma unroll
        for (int ni = 0; ni < 4; ++ni) {
            int col = wc + (ni << 4) + l15;
            #pragma unroll
            for (int j = 0; j < 4; ++j) {
                int row = wr + (mi << 4) + (lg << 2) + j;
                *(unsigned short*)(smem + row * 256 + ((col * 2) ^ ((row & 7) << 4))) =
                    f2bf(acc[mi][ni][j]);
            }
        }
    }
    __syncthreads();

    // ---- Wh1 = Wh.a1, Wh2 = Wh.a2 (2 threads per row) ----
    {
        int r = t >> 1;
        int cb = (t & 1) << 6;
        float s1 = 0.f, s2 = 0.f;
        #pragma unroll
        for (int i = 0; i < 8; ++i) {
            int c = cb + (i << 3);
            short8 wv = *(const short8*)(smem + r * 256 + ((c * 2) ^ ((r & 7) << 4)));
            #pragma unroll
            for (int j = 0; j < 8; ++j) {
                float w = bf2f((unsigned short)wv[j]);
                s1 += w * a_s[c + j];
                s2 += w * a_s[128 + c + j];
            }
        }
        s1 += __shfl_xor(s1, 1);
        s2 += __shfl_xor(s2, 1);
        if ((t & 1) == 0) { wh1_s[r] = s1; wh2_s[r] = s2; }
    }
    __syncthreads();

    // ---- attention coefficients per output row ----
    if (t < 128) {
        int r = t;
        if (r >= 1 && r <= out_rows) {
            int g = row_start + r - 1;
            const int* mr = opm + ((size_t)b * N + g) * 3;
            float w1 = wh1_s[r];
            float e0 = w1 + wh2_s[r - 1];   // k=0: prev
            float e1 = w1 + wh2_s[r];       // k=1: self
            float e2 = w1 + wh2_s[r + 1];   // k=2: next
            e0 = e0 > 0.f ? e0 : ALPHA * e0;
            e1 = e1 > 0.f ? e1 : ALPHA * e1;
            e2 = e2 > 0.f ? e2 : ALPHA * e2;
            if (mr[0] > 0) e0 = NEG_INF;
            if (mr[1] > 0) e1 = NEG_INF;
            if (mr[2] > 0) e2 = NEG_INF;
            float m = fmaxf(e0, fmaxf(e1, e2));
            float x0 = expf(e0 - m), x1 = expf(e1 - m), x2 = expf(e2 - m);
            float inv = 1.f / (x0 + x1 + x2);
            att_s[r][0] = x0 * inv;
            att_s[r][1] = x1 * inv;
            att_s[r][2] = x2 * inv;
        }
    }
    __syncthreads();

    // ---- combine: out[n] = att0*Wh[n-1] + att1*Wh[n] + att2*Wh[n+1] ----
    // 32 lanes per row, 4 bf16 cols per lane (8B ds_read_b64 per row).
    for (int it = 0; it < 16; ++it) {
        int r = 1 + (t >> 5) + (it << 3);
        if (r > out_rows) continue;
        int c = (t & 31) << 2;
        float a0 = att_s[r][0], a1 = att_s[r][1], a2 = att_s[r][2];
        ushort4 wm = *(const ushort4*)(smem + (r - 1) * 256 + ((c * 2) ^ (((r - 1) & 7) << 4)));
        ushort4 w0 = *(const ushort4*)(smem + r * 256 + ((c * 2) ^ ((r & 7) << 4)));
        ushort4 wp = *(const ushort4*)(smem + (r + 1) * 256 + ((c * 2) ^ (((r + 1) & 7) << 4)));
        f32x4 res;
        res[0] = a0 * bf2f(wm.x) + a1 * bf2f(w0.x) + a2 * bf2f(wp.x);
        res[1] = a0 * bf2f(wm.y) + a1 * bf2f(w0.y) + a2 * bf2f(wp.y);
        res[2] = a0 * bf2f(wm.z) + a1 * bf2f(w0.z) + a2 * bf2f(wp.z);
        res[3] = a0 * bf2f(wm.w) + a1 * bf2f(w0.w) + a2 * bf2f(wp.w);
        int g = row_start + r - 1;
        *(f32x4*)(outB + (size_t)g * 128 + c) = res;
    }
}

extern "C" void kernel_launch(void* const* d_in, const int* in_sizes, int n_in,
                              void* d_out, int out_size, void* d_ws, size_t ws_size,
                              hipStream_t stream) {
    const float* h   = (const float*)d_in[0];
    const int*   opm = (const int*)d_in[1];
    const float* W   = (const float*)d_in[2];
    const float* a   = (const float*)d_in[3];
    float* out = (float*)d_out;
    unsigned short* ws = (unsigned short*)d_ws;
    const int N = 65536;
    const int B = 4;
    prep_wt<<<8, 256, 0, stream>>>(W, ws);
    dim3 grid((N + OUT_ROWS - 1) / OUT_ROWS, B);
    gat_fused<<<grid, 256, 0, stream>>>(h, opm, ws, a, out, N);
}

// Round 3
// 64.615 us; speedup vs baseline: 1.0103x; 1.0103x over previous
//
#include <hip/hip_runtime.h>
#include <hip/hip_bf16.h>

typedef __attribute__((ext_vector_type(8))) short short8;
typedef __attribute__((ext_vector_type(4))) float f32x4;

#define ALPHA 0.2f
#define NEG_INF -9e15f
#define OUT_ROWS 126
#define NTILES 521            // ceil(65536 / 126)
#define NB 4
#define NN 65536

typedef __attribute__((address_space(3))) void as3_void;
typedef const __attribute__((address_space(1))) void as1_void;

__device__ __forceinline__ short fb(float x) {
    __hip_bfloat16 b = __float2bfloat16(x);
    return __builtin_bit_cast(short, b);
}

// ---- prep: W -> bf16 B-fragment table; [Wa1 Wa2 0..] -> B2 fragment table ----
// B frag fi = (wcg*4 + kk)*4 + ni, lane: elem j = W[kk*32+lg*8+j][wcg*64+ni*16+l15]
// B2 frag kk, lane: elem j = (l15==0 ? Wa1 : l15==1 ? Wa2 : 0)[kk*32+lg*8+j]
__global__ __launch_bounds__(256) void prep_w(const float* __restrict__ W,
                                              const float* __restrict__ a,
                                              unsigned short* __restrict__ ws) {
    const int t = threadIdx.x;
    if (blockIdx.x < 8) {
        int q = blockIdx.x * 256 + t;
        int lane = q & 63, fi = q >> 6;
        int ni = fi & 3, kk = (fi >> 2) & 3, wcg = fi >> 4;
        int n = wcg * 64 + ni * 16 + (lane & 15);
        int k0 = kk * 32 + ((lane >> 4) & 3) * 8;
        short8 o;
        #pragma unroll
        for (int j = 0; j < 8; ++j) o[j] = fb(W[(k0 + j) * 128 + n]);
        *(short8*)(ws + (size_t)q * 8) = o;
    } else {
        __shared__ float wa[2][128];
        {
            int k = t >> 1, sel = t & 1;
            const f32x4* wr4 = (const f32x4*)(W + k * 128);
            const f32x4* av4 = (const f32x4*)(a + sel * 128);
            float s = 0.f;
            #pragma unroll
            for (int c4 = 0; c4 < 32; ++c4) {
                f32x4 wv = wr4[c4], av = av4[c4];
                s += wv[0]*av[0] + wv[1]*av[1] + wv[2]*av[2] + wv[3]*av[3];
            }
            wa[sel][k] = s;
        }
        __syncthreads();
        {
            int lane = t & 63, kk = t >> 6;
            int l15 = lane & 15, lg = (lane >> 4) & 3;
            int k0 = kk * 32 + lg * 8;
            short8 o;
            #pragma unroll
            for (int j = 0; j < 8; ++j) {
                float v = (l15 < 2) ? wa[l15][k0 + j] : 0.f;
                o[j] = fb(v);
            }
            *(short8*)(ws + 16384 + (size_t)t * 8) = o;
        }
    }
}

// One block = 126 output rows of one batch. h staged f32 via global_load_lds
// (pre-swizzled source), bf16 MFMA GEMM (B frags from L2-resident table),
// Wh1/Wh2 via extra MFMA column, f32 Wh spill in-place, windowed softmax,
// combine with non-temporal stores.
__global__ __launch_bounds__(256, 2)
void gat_fused(const float* __restrict__ h, const int* __restrict__ opm,
               const unsigned short* __restrict__ ws, float* __restrict__ out) {
    __shared__ __align__(16) char smem[65536];   // h tile f32 -> Wh f32 (swizzled)
    __shared__ float wh1_s[128];
    __shared__ float wh2_s[128];
    __shared__ float att_s[128][4];

    const int t = threadIdx.x;
    // bijective XCD swizzle: nwg = 2084 = 8*260 + 4  (m204 formula)
    int orig = blockIdx.x;
    int xcd = orig & 7, idx = orig >> 3;
    int wgid = (xcd < 4 ? xcd * 261 : 1044 + (xcd - 4) * 260) + idx;
    const int b = wgid / NTILES;
    const int tile = wgid - b * NTILES;
    const int row_start = tile * OUT_ROWS;
    const int out_rows = min(OUT_ROWS, NN - row_start);
    const float* hB = h + (size_t)b * NN * 128;
    float* outB = out + (size_t)b * NN * 128;

    const int lane = t & 63;
    const int wave = t >> 6;

    // hoisted mask loads (used in attention phase, issued early)
    int m0 = 0, m1 = 0, m2 = 0;
    if (t >= 1 && t <= out_rows) {
        const int* mr = opm + ((size_t)b * NN + row_start + t - 1) * 3;
        m0 = mr[0]; m1 = mr[1]; m2 = mr[2];
    }

    // ---- stage h tile (f32) -> LDS via global_load_lds, source pre-swizzled ----
    {
        const char* hC = (const char*)hB;
        #pragma unroll
        for (int i = 0; i < 16; ++i) {
            int rpair = (wave << 4) + i;          // 2 rows per instruction
            int r = (rpair << 1) + (lane >> 5);
            int g = row_start - 1 + r;
            if (g < 0) g += NN;
            if (g >= NN) g -= NN;
            const char* src = hC + (size_t)g * 512 +
                              (((lane & 31) << 4) ^ ((r & 7) << 4));
            char* dst = smem + (rpair << 10);     // wave-uniform, linear
            __builtin_amdgcn_global_load_lds((as1_void*)src, (as3_void*)dst, 16, 0, 0);
        }
    }
    __syncthreads();

    // ---- GEMM: Wh = hTile @ W (+ extra column frag -> Wh1/Wh2) ----
    const int l15 = lane & 15;
    const int lg = (lane >> 4) & 3;
    const int wr = (wave >> 1) << 6;
    const int wcg = wave & 1;
    const int wc = wcg << 6;

    f32x4 acc[4][4];
    f32x4 acc2[4];
    #pragma unroll
    for (int mi = 0; mi < 4; ++mi) {
        acc2[mi] = (f32x4){0.f, 0.f, 0.f, 0.f};
        #pragma unroll
        for (int ni = 0; ni < 4; ++ni)
            acc[mi][ni] = (f32x4){0.f, 0.f, 0.f, 0.f};
    }

    const short8* wsv  = (const short8*)ws;
    const short8* wsv2 = (const short8*)(ws + 16384);
    #pragma unroll
    for (int kk = 0; kk < 4; ++kk) {
        short8 bfr[4], bfr2;
        #pragma unroll
        for (int ni = 0; ni < 4; ++ni)
            bfr[ni] = wsv[((((wcg << 2) + kk) << 2) + ni) * 64 + lane];
        bfr2 = wsv2[(kk << 6) + lane];
        int kb = (kk << 7) + (lg << 5);           // byte offset along K
        short8 af[4];
        #pragma unroll
        for (int mi = 0; mi < 4; ++mi) {
            int m = wr + (mi << 4) + l15;
            int sw = (m & 7) << 4;
            const char* base = smem + m * 512;
            f32x4 lo = *(const f32x4*)(base + (kb ^ sw));
            f32x4 hi = *(const f32x4*)(base + ((kb + 16) ^ sw));
            short8 v;
            v[0] = fb(lo[0]); v[1] = fb(lo[1]); v[2] = fb(lo[2]); v[3] = fb(lo[3]);
            v[4] = fb(hi[0]); v[5] = fb(hi[1]); v[6] = fb(hi[2]); v[7] = fb(hi[3]);
            af[mi] = v;
        }
        #pragma unroll
        for (int mi = 0; mi < 4; ++mi) {
            #pragma unroll
            for (int ni = 0; ni < 4; ++ni)
                acc[mi][ni] = __builtin_amdgcn_mfma_f32_16x16x32_bf16(
                    af[mi], bfr[ni], acc[mi][ni], 0, 0, 0);
            acc2[mi] = __builtin_amdgcn_mfma_f32_16x16x32_bf16(
                af[mi], bfr2, acc2[mi], 0, 0, 0);
        }
    }
    __syncthreads();

    // ---- spill Wh (f32, swizzled) in place; Wh1/Wh2 from acc2 ----
    // C/D layout: col = lane&15, row = (lane>>4)*4 + reg  [HW-verified]
    #pragma unroll
    for (int mi = 0; mi < 4; ++mi)
        #pragma unroll
        for (int ni = 0; ni < 4; ++ni) {
            int col = wc + (ni << 4) + l15;
            #pragma unroll
            for (int j = 0; j < 4; ++j) {
                int row = wr + (mi << 4) + (lg << 2) + j;
                *(float*)(smem + row * 512 + ((col << 2) ^ ((row & 7) << 4))) =
                    acc[mi][ni][j];
            }
        }
    if (l15 < 2) {
        float* dv = (l15 == 0) ? wh1_s : wh2_s;   // waves 0/1 (2/3) write identical values
        #pragma unroll
        for (int mi = 0; mi < 4; ++mi)
            #pragma unroll
            for (int j = 0; j < 4; ++j)
                dv[wr + (mi << 4) + (lg << 2) + j] = acc2[mi][j];
    }
    __syncthreads();

    // ---- attention coefficients ----
    if (t >= 1 && t <= out_rows) {
        float w1 = wh1_s[t];
        float e0 = w1 + wh2_s[t - 1];
        float e1 = w1 + wh2_s[t];
        float e2 = w1 + wh2_s[t + 1];
        e0 = e0 > 0.f ? e0 : ALPHA * e0;
        e1 = e1 > 0.f ? e1 : ALPHA * e1;
        e2 = e2 > 0.f ? e2 : ALPHA * e2;
        if (m0 > 0) e0 = NEG_INF;
        if (m1 > 0) e1 = NEG_INF;
        if (m2 > 0) e2 = NEG_INF;
        float m = fmaxf(e0, fmaxf(e1, e2));
        float x0 = __expf(e0 - m), x1 = __expf(e1 - m), x2 = __expf(e2 - m);
        float inv = 1.f / (x0 + x1 + x2);
        att_s[t][0] = x0 * inv;
        att_s[t][1] = x1 * inv;
        att_s[t][2] = x2 * inv;
    }
    __syncthreads();

    // ---- combine + non-temporal store ----
    #pragma unroll
    for (int it = 0; it < 16; ++it) {
        int rr = 1 + (t >> 5) + (it << 3);
        if (rr > out_rows) continue;
        int cb = (t & 31) << 4;
        float a0 = att_s[rr][0], a1 = att_s[rr][1], a2 = att_s[rr][2];
        f32x4 wm = *(const f32x4*)(smem + (rr - 1) * 512 + (cb ^ (((rr - 1) & 7) << 4)));
        f32x4 w0 = *(const f32x4*)(smem + rr * 512 + (cb ^ ((rr & 7) << 4)));
        f32x4 wp = *(const f32x4*)(smem + (rr + 1) * 512 + (cb ^ (((rr + 1) & 7) << 4)));
        f32x4 res;
        #pragma unroll
        for (int j = 0; j < 4; ++j)
            res[j] = a0 * wm[j] + a1 * w0[j] + a2 * wp[j];
        float* op = outB + (size_t)(row_start + rr - 1) * 128 + ((t & 31) << 2);
        __builtin_nontemporal_store(res, (f32x4*)op);
    }
}

extern "C" void kernel_launch(void* const* d_in, const int* in_sizes, int n_in,
                              void* d_out, int out_size, void* d_ws, size_t ws_size,
                              hipStream_t stream) {
    const float* h   = (const float*)d_in[0];
    const int*   opm = (const int*)d_in[1];
    const float* W   = (const float*)d_in[2];
    const float* a   = (const float*)d_in[3];
    float* out = (float*)d_out;
    unsigned short* ws = (unsigned short*)d_ws;
    prep_w<<<9, 256, 0, stream>>>(W, a, ws);
    gat_fused<<<NTILES * NB, 256, 0, stream>>>(h, opm, ws, out);
}